// Round 1
// baseline (234.344 us; speedup 1.0000x reference)
//
#include <hip/hip_runtime.h>

// Decoder (DA-RNN style): B=256 independent sequences, T=32 steps.
// One block per batch element, 512 threads (8 waves), all 32 steps in-block.
// W1a (128x256) and W_hh (512x128) held in registers (~192 VGPR persistent);
// Epre = W1b @ enc precomputed once (time-invariant across the scan).

#define BB 256
#define TT 32
#define ENC 128
#define DEC 128
#define NG 512 // 4*DEC

__device__ __forceinline__ float sigmoidf_(float x) {
    return 1.f / (1.f + __expf(-x));
}
__device__ __forceinline__ float tanhf_(float x) {
    x = fminf(fmaxf(x, -15.f), 15.f);
    float e = __expf(2.f * x);
    return (e - 1.f) / (e + 1.f);
}
__device__ __forceinline__ float dot4(float4 a, float4 b) {
    return a.x * b.x + a.y * b.y + a.z * b.z + a.w * b.w;
}

__global__ __launch_bounds__(512, 2) void decoder_kernel(
    const float* __restrict__ enc_g,  // [B,T,ENC]
    const float* __restrict__ yh_g,   // [B,T,1]
    const float* __restrict__ W1,     // [128,384]  (cols: [h(128) | c(128) | enc(128)])
    const float* __restrict__ b1,     // [128]
    const float* __restrict__ W2,     // [1,128]
    const float* __restrict__ b2,     // [1]
    const float* __restrict__ Wih,    // [512,1]
    const float* __restrict__ Whh,    // [512,128]
    const float* __restrict__ bih,    // [512]
    const float* __restrict__ bhh,    // [512]
    const float* __restrict__ fcW,    // [1,129]
    const float* __restrict__ fcB,    // [1]
    const float* __restrict__ fcfW,   // [1,256]
    const float* __restrict__ fcfB,   // [1]
    float* __restrict__ out)          // [B,1]
{
    __shared__ float s_enc[TT * ENC];   // 16KB, input slice for this batch
    __shared__ float s_epre[TT * ENC];  // 16KB, W1b@enc + b1 (time-invariant)
    __shared__ float s_hc[2 * DEC];     // h | c
    __shared__ float s_A[ENC];          // W1a @ [h;c]
    __shared__ float s_logit[TT];
    __shared__ float s_gate[NG];
    __shared__ float s_w2[ENC];
    __shared__ float s_fcw[132];
    __shared__ float s_fcfw[256];
    __shared__ float s_yh[TT];
    __shared__ float s_ytilde;

    const int tid = threadIdx.x;
    const int b = blockIdx.x;
    const int lane = tid & 63;
    const int hrow = tid >> 2;  // 0..127 (attn hidden row)
    const int seg = tid & 3;    // 4 threads per row

    // ---- stage inputs / small weights ----
    const float4* encp = (const float4*)(enc_g + (size_t)b * TT * ENC);
    float4* s_enc4 = (float4*)s_enc;
    s_enc4[tid * 2] = encp[tid * 2];
    s_enc4[tid * 2 + 1] = encp[tid * 2 + 1];
    if (tid < 2 * DEC) s_hc[tid] = 0.f;
    if (tid < ENC) s_w2[tid] = W2[tid];
    if (tid < 129) s_fcw[tid] = fcW[tid];
    if (tid < 256) s_fcfw[tid] = fcfW[tid];
    if (tid < TT) s_yh[tid] = yh_g[b * TT + tid];
    const float b2v = b2[0];
    const float fcbv = fcB[0];
    const float fcfbv = fcfB[0];
    const float b1v = b1[hrow];
    __syncthreads();

    // ---- Epre[t][h] = b1[h] + sum_e W1[h][256+e] * enc[t][e]  (once) ----
    {
        const float4* w1bp = (const float4*)(W1 + hrow * 384 + 256 + seg * 32);
        float4 w1b[8];
#pragma unroll
        for (int k = 0; k < 8; k++) w1b[k] = w1bp[k];
        for (int t = 0; t < TT; t++) {
            float p = 0.f;
#pragma unroll
            for (int k = 0; k < 8; k++) p += dot4(w1b[k], s_enc4[t * 32 + seg * 8 + k]);
            p += __shfl_xor(p, 1);
            p += __shfl_xor(p, 2);
            if (seg == 0) s_epre[t * ENC + hrow] = p + b1v;
        }
    }

    // ---- persistent register weights ----
    float4 w1a[16];  // W1a[hrow][seg*64 .. +64)
    {
        const float4* w1ap = (const float4*)(W1 + hrow * 384 + seg * 64);
#pragma unroll
        for (int k = 0; k < 16; k++) w1a[k] = w1ap[k];
    }
    float4 whh[32];  // W_hh[tid][:]
    {
        const float4* whhp = (const float4*)(Whh + tid * DEC);
#pragma unroll
        for (int k = 0; k < 32; k++) whh[k] = whhp[k];
    }
    const float wihv = Wih[tid];
    const float biasg = bih[tid] + bhh[tid];

    const float4* s_hc4 = (const float4*)s_hc;
    float ctxl = 0.f, ctxh = 0.f;  // wave0: ctx[lane], ctx[lane+64]
    __syncthreads();

    // ---- scan over 32 timesteps ----
    for (int t = 0; t < TT; t++) {
        // A[hrow] = sum_{e<256} W1a[hrow][e] * hc[e]
        {
            float p = 0.f;
#pragma unroll
            for (int k = 0; k < 16; k++) p += dot4(w1a[k], s_hc4[seg * 16 + k]);
            p += __shfl_xor(p, 1);
            p += __shfl_xor(p, 2);
            if (seg == 0) s_A[hrow] = p;
        }
        __syncthreads();

        // logits[tt2] = b2 + sum_h W2[h]*tanh(A[h] + Epre[tt2][h])
        {
            const int tt2 = tid >> 4, hg = tid & 15;
            const float4* sA4 = (const float4*)s_A;
            const float4* sE4 = (const float4*)(s_epre + tt2 * ENC);
            const float4* sW4 = (const float4*)s_w2;
            float lp = 0.f;
#pragma unroll
            for (int q = 0; q < 2; q++) {
                float4 a = sA4[hg * 2 + q];
                float4 e = sE4[hg * 2 + q];
                float4 w = sW4[hg * 2 + q];
                lp += w.x * tanhf_(a.x + e.x) + w.y * tanhf_(a.y + e.y) +
                      w.z * tanhf_(a.z + e.z) + w.w * tanhf_(a.w + e.w);
            }
            lp += __shfl_xor(lp, 1);
            lp += __shfl_xor(lp, 2);
            lp += __shfl_xor(lp, 4);
            lp += __shfl_xor(lp, 8);
            if (hg == 0) s_logit[tt2] = lp + b2v;
        }
        __syncthreads();

        // wave0 serial chain: softmax -> ctx -> y_tilde (no extra barriers)
        if (tid < 64) {
            float lg = (lane < TT) ? s_logit[lane] : -1e30f;
            float m = lg;
            m = fmaxf(m, __shfl_xor(m, 1));
            m = fmaxf(m, __shfl_xor(m, 2));
            m = fmaxf(m, __shfl_xor(m, 4));
            m = fmaxf(m, __shfl_xor(m, 8));
            m = fmaxf(m, __shfl_xor(m, 16));
            float e = (lane < TT) ? __expf(lg - m) : 0.f;
            float s = e;
            s += __shfl_xor(s, 1);
            s += __shfl_xor(s, 2);
            s += __shfl_xor(s, 4);
            s += __shfl_xor(s, 8);
            s += __shfl_xor(s, 16);
            float av = e / s;  // attn weight in lanes 0..31
            ctxl = 0.f;
            ctxh = 0.f;
            for (int q = 0; q < TT; q++) {
                float a = __shfl(av, q);
                ctxl += a * s_enc[q * ENC + lane];
                ctxh += a * s_enc[q * ENC + 64 + lane];
            }
            float yp = s_fcw[lane] * ctxl + s_fcw[64 + lane] * ctxh;
            yp += __shfl_xor(yp, 1);
            yp += __shfl_xor(yp, 2);
            yp += __shfl_xor(yp, 4);
            yp += __shfl_xor(yp, 8);
            yp += __shfl_xor(yp, 16);
            yp += __shfl_xor(yp, 32);
            if (lane == 0) s_ytilde = yp + s_fcw[128] * s_yh[t] + fcbv;
        }
        __syncthreads();

        // gates[tid] = y_tilde*Wih[tid] + b + sum_k Whh[tid][k]*h[k]
        {
            float dotv = 0.f;
#pragma unroll
            for (int k = 0; k < 32; k++) dotv += dot4(whh[k], s_hc4[k]);
            s_gate[tid] = s_ytilde * wihv + biasg + dotv;
        }
        __syncthreads();

        // LSTM pointwise update (gate order i,f,g,o)
        if (tid < DEC) {
            float gi = s_gate[tid];
            float gf = s_gate[DEC + tid];
            float gg = s_gate[2 * DEC + tid];
            float go = s_gate[3 * DEC + tid];
            float cn = sigmoidf_(gf) * s_hc[DEC + tid] + sigmoidf_(gi) * tanhf_(gg);
            float hn = sigmoidf_(go) * tanhf_(cn);
            s_hc[tid] = hn;
            s_hc[DEC + tid] = cn;
        }
        __syncthreads();
    }

    // out[b] = fcf_b + fcfW[0:128]@h + fcfW[128:256]@ctx + y_hist[b,31]
    if (tid < 64) {
        float p = s_fcfw[lane] * s_hc[lane] + s_fcfw[64 + lane] * s_hc[64 + lane] +
                  s_fcfw[128 + lane] * ctxl + s_fcfw[192 + lane] * ctxh;
        p += __shfl_xor(p, 1);
        p += __shfl_xor(p, 2);
        p += __shfl_xor(p, 4);
        p += __shfl_xor(p, 8);
        p += __shfl_xor(p, 16);
        p += __shfl_xor(p, 32);
        if (lane == 0) out[b] = p + fcfbv + s_yh[TT - 1];
    }
}

extern "C" void kernel_launch(void* const* d_in, const int* in_sizes, int n_in,
                              void* d_out, int out_size, void* d_ws, size_t ws_size,
                              hipStream_t stream) {
    decoder_kernel<<<BB, 512, 0, stream>>>(
        (const float*)d_in[0],   // input_encoded
        (const float*)d_in[1],   // y_history
        (const float*)d_in[2],   // attn_W1
        (const float*)d_in[3],   // attn_b1
        (const float*)d_in[4],   // attn_W2
        (const float*)d_in[5],   // attn_b2
        (const float*)d_in[6],   // W_ih
        (const float*)d_in[7],   // W_hh
        (const float*)d_in[8],   // b_ih
        (const float*)d_in[9],   // b_hh
        (const float*)d_in[10],  // fc_W
        (const float*)d_in[11],  // fc_b
        (const float*)d_in[12],  // fcf_W
        (const float*)d_in[13],  // fcf_b
        (float*)d_out);
}

// Round 2
// 218.948 us; speedup vs baseline: 1.0703x; 1.0703x over previous
//
#include <hip/hip_runtime.h>

// DA-RNN decoder: B=256 blocks (1/CU), 512 threads, 32 sequential steps in-block.
// Weights register-resident: wg (Whh slice, 128 VGPR) + w1a (64 VGPR); pinned via
// amdgpu_waves_per_eu(2,2) (grid is exactly 1 block/CU = 2 waves/EU, so no
// occupancy loss). All per-step LDS access patterns are <=2-way conflicts.

#define BB 256
#define TT 32
#define ENC 128
#define DEC 128
#define NG 512
#define PE 132  // padded epre/Ad/w2d row stride (floats): 16-way -> 2-way
#define ER 36   // enc row stride in float4 units (144 floats): seg conflicts -> 0
#define HC 17   // hc chunk stride in float4 units (68 floats): seg conflicts -> 0

__device__ __forceinline__ float fast_tanh(float x) {
    x = fminf(fmaxf(x, -15.f), 15.f);
    float e = __expf(2.f * x);
    return 1.f - __fdividef(2.f, e + 1.f);
}
__device__ __forceinline__ float fast_sig(float x) {
    return __fdividef(1.f, 1.f + __expf(-x));
}
__device__ __forceinline__ float dot4(float4 a, float4 b) {
    return a.x * b.x + a.y * b.y + a.z * b.z + a.w * b.w;
}

__global__ __launch_bounds__(512) __attribute__((amdgpu_waves_per_eu(2, 2)))
void decoder_kernel(
    const float* __restrict__ enc_g,  // [B,T,ENC]
    const float* __restrict__ yh_g,   // [B,T,1]
    const float* __restrict__ W1,     // [128,384] cols: [h|c|enc]
    const float* __restrict__ b1,     // [128]
    const float* __restrict__ W2,     // [1,128]
    const float* __restrict__ b2,     // [1]
    const float* __restrict__ Wih,    // [512,1]
    const float* __restrict__ Whh,    // [512,128]
    const float* __restrict__ bih,    // [512]
    const float* __restrict__ bhh,    // [512]
    const float* __restrict__ fcW,    // [1,129]
    const float* __restrict__ fcB,    // [1]
    const float* __restrict__ fcfW,   // [1,256]
    const float* __restrict__ fcfB,   // [1]
    float* __restrict__ out)          // [B,1]
{
    __shared__ float s_enc[TT * ER * 4];  // [t][4 chunks x 36 floats] 18.4KB
    __shared__ float s_epre[TT * PE];     // 16.9KB  (W1b@enc + b1, time-invariant)
    __shared__ float s_hcp[4 * HC * 4];   // [h;c] in 4 chunks of 64 @ stride 68
    __shared__ float s_Ad[4 * PE];        // A duplicated per tt%4 group
    __shared__ float s_w2d[4 * PE];       // W2 duplicated per tt%4 group
    __shared__ float s_logit[TT];
    __shared__ float s_gdot[NG];          // bias + Whh@h
    __shared__ float s_wih[NG];
    __shared__ float s_fcw[132];
    __shared__ float s_fcfw[256];
    __shared__ float s_yh[TT];
    __shared__ float s_ytilde;

    const int tid = threadIdx.x;
    const int b = blockIdx.x;
    const int lane = tid & 63;
    const int g = tid >> 2;  // row group 0..127
    const int s = tid & 3;   // 4-way column split

    // ---- stage enc into chunked layout ----
    const float4* encp = (const float4*)(enc_g + (size_t)b * TT * ENC);
    float4* senc4 = (float4*)s_enc;
#pragma unroll
    for (int r = 0; r < 2; r++) {
        int gi = tid * 2 + r;  // 0..1023
        int t = gi >> 5, e4 = gi & 31;
        senc4[t * ER + (e4 >> 3) * 9 + (e4 & 7)] = encp[gi];
    }
    if (tid < 4 * HC * 4) s_hcp[tid] = 0.f;
    if (tid < ENC) {
        float v = W2[tid];
#pragma unroll
        for (int r = 0; r < 4; r++) s_w2d[r * PE + tid] = v;
    }
    if (tid < 129) s_fcw[tid] = fcW[tid];
    if (tid < 256) s_fcfw[tid] = fcfW[tid];
    if (tid < TT) s_yh[tid] = yh_g[b * TT + tid];
    s_wih[tid] = Wih[tid];
    const float b2v = b2[0];
    const float fcbv = fcB[0];
    const float fcfbv = fcfB[0];
    const float b1v = b1[g];
    __syncthreads();

    // ---- Epre[t][h] = b1[h] + W1[:,256:384] @ enc[t]  (once) ----
    {
        const float4* w1bp = (const float4*)(W1 + g * 384 + 256 + s * 32);
        float4 w1b[8];
#pragma unroll
        for (int k = 0; k < 8; k++) w1b[k] = w1bp[k];
        for (int t = 0; t < TT; t++) {
            float p = 0.f;
#pragma unroll
            for (int k = 0; k < 8; k++) p += dot4(w1b[k], senc4[t * ER + s * 9 + k]);
            p += __shfl_xor(p, 1);
            p += __shfl_xor(p, 2);
            if (s == 0) s_epre[t * PE + g] = p + b1v;
        }
    }

    // ---- persistent register weights ----
    float4 w1a[16];  // W1[g][s*64 .. +64)
    {
        const float4* p = (const float4*)(W1 + g * 384 + s * 64);
#pragma unroll
        for (int k = 0; k < 16; k++) w1a[k] = p[k];
    }
    float4 wg[4][8];  // Whh[j*128+g][s*32 .. +32)
    float bg4[4];
#pragma unroll
    for (int j = 0; j < 4; j++) {
        const float4* p = (const float4*)(Whh + (size_t)(j * 128 + g) * 128 + s * 32);
#pragma unroll
        for (int k = 0; k < 8; k++) wg[j][k] = p[k];
        bg4[j] = bih[j * 128 + g] + bhh[j * 128 + g];
    }

    const float4* hc4 = (const float4*)s_hcp;
    float ctxl = 0.f, ctxh = 0.f;  // wave0 registers: ctx[lane], ctx[64+lane]
    __syncthreads();

    // ---- scan ----
    for (int t = 0; t < TT; t++) {
        // phase1: A = W1a@[h;c]  and  gdot = bias + Whh@h (independent, parallel)
        float pA = 0.f;
#pragma unroll
        for (int k = 0; k < 16; k++) pA += dot4(w1a[k], hc4[s * HC + k]);
        float4 hv[8];
#pragma unroll
        for (int k = 0; k < 8; k++) hv[k] = hc4[(s >> 1) * HC + (s & 1) * 8 + k];
        float p0 = 0.f, p1 = 0.f, p2 = 0.f, p3 = 0.f;
#pragma unroll
        for (int k = 0; k < 8; k++) {
            p0 += dot4(wg[0][k], hv[k]);
            p1 += dot4(wg[1][k], hv[k]);
            p2 += dot4(wg[2][k], hv[k]);
            p3 += dot4(wg[3][k], hv[k]);
        }
        pA += __shfl_xor(pA, 1);
        pA += __shfl_xor(pA, 2);
        p0 += __shfl_xor(p0, 1);
        p0 += __shfl_xor(p0, 2);
        p1 += __shfl_xor(p1, 1);
        p1 += __shfl_xor(p1, 2);
        p2 += __shfl_xor(p2, 1);
        p2 += __shfl_xor(p2, 2);
        p3 += __shfl_xor(p3, 1);
        p3 += __shfl_xor(p3, 2);
        if (s == 0) {
#pragma unroll
            for (int r = 0; r < 4; r++) s_Ad[r * PE + g] = pA;
            s_gdot[g] = p0 + bg4[0];
            s_gdot[128 + g] = p1 + bg4[1];
            s_gdot[256 + g] = p2 + bg4[2];
            s_gdot[384 + g] = p3 + bg4[3];
        }
        __syncthreads();

        // phase2: logits[tt] = b2 + sum_h W2[h]*tanh(A[h]+Epre[tt][h])
        {
            const int tt = tid >> 4, hg = tid & 15;
            const float* Ab = s_Ad + (tt & 3) * PE + hg * 8;
            const float* Eb = s_epre + tt * PE + hg * 8;
            const float* Wb = s_w2d + (tt & 3) * PE + hg * 8;
            float lp = 0.f;
#pragma unroll
            for (int q = 0; q < 2; q++) {
                float4 a = *(const float4*)(Ab + q * 4);
                float4 e = *(const float4*)(Eb + q * 4);
                float4 w = *(const float4*)(Wb + q * 4);
                lp += w.x * fast_tanh(a.x + e.x) + w.y * fast_tanh(a.y + e.y) +
                      w.z * fast_tanh(a.z + e.z) + w.w * fast_tanh(a.w + e.w);
            }
            lp += __shfl_xor(lp, 1);
            lp += __shfl_xor(lp, 2);
            lp += __shfl_xor(lp, 4);
            lp += __shfl_xor(lp, 8);
            if (hg == 0) s_logit[tt] = lp + b2v;
        }
        __syncthreads();

        // phase3 (wave0): softmax (no max-sub: |logit|<=~5) -> ctx -> y_tilde
        if (tid < 64) {
            float e = (lane < TT) ? __expf(s_logit[lane]) : 0.f;
            float ssum = e;
            ssum += __shfl_xor(ssum, 1);
            ssum += __shfl_xor(ssum, 2);
            ssum += __shfl_xor(ssum, 4);
            ssum += __shfl_xor(ssum, 8);
            ssum += __shfl_xor(ssum, 16);
            float av = __fdividef(e, ssum);  // attn weight, lanes 0..31
            const int offl = (lane >> 5) * 36 + (lane & 31);
            const int offh = (2 + (lane >> 5)) * 36 + (lane & 31);
            float cl = 0.f, ch = 0.f;
#pragma unroll
            for (int q = 0; q < TT; q++) {
                float a = __shfl(av, q);
                cl += a * s_enc[q * 144 + offl];
                ch += a * s_enc[q * 144 + offh];
            }
            ctxl = cl;  // == ctx[lane]
            ctxh = ch;  // == ctx[64+lane]
            float yp = s_fcw[lane] * cl + s_fcw[64 + lane] * ch;
            yp += __shfl_xor(yp, 1);
            yp += __shfl_xor(yp, 2);
            yp += __shfl_xor(yp, 4);
            yp += __shfl_xor(yp, 8);
            yp += __shfl_xor(yp, 16);
            yp += __shfl_xor(yp, 32);
            if (lane == 0) s_ytilde = yp + s_fcw[128] * s_yh[t] + fcbv;
        }
        __syncthreads();

        // phase4: gates finish + LSTM pointwise (i,f,g,o)
        if (tid < DEC) {
            float yt = s_ytilde;
            float gi = s_gdot[tid] + s_wih[tid] * yt;
            float gf = s_gdot[128 + tid] + s_wih[128 + tid] * yt;
            float gg = s_gdot[256 + tid] + s_wih[256 + tid] * yt;
            float go = s_gdot[384 + tid] + s_wih[384 + tid] * yt;
            const int ch_ = tid >> 6, of_ = tid & 63;
            float c_old = s_hcp[(2 + ch_) * 68 + of_];
            float cn = fast_sig(gf) * c_old + fast_sig(gi) * fast_tanh(gg);
            float hn = fast_sig(go) * fast_tanh(cn);
            s_hcp[ch_ * 68 + of_] = hn;
            s_hcp[(2 + ch_) * 68 + of_] = cn;
        }
        __syncthreads();
    }

    // ---- out[b] = fcf_b + fcfW[0:128]@h + fcfW[128:256]@ctx + y_hist[b,31] ----
    if (tid < 64) {
        float h0 = s_hcp[lane];       // h[lane]      (chunk 0)
        float h1 = s_hcp[68 + lane];  // h[64+lane]   (chunk 1)
        float p = s_fcfw[lane] * h0 + s_fcfw[64 + lane] * h1 +
                  s_fcfw[128 + lane] * ctxl + s_fcfw[192 + lane] * ctxh;
        p += __shfl_xor(p, 1);
        p += __shfl_xor(p, 2);
        p += __shfl_xor(p, 4);
        p += __shfl_xor(p, 8);
        p += __shfl_xor(p, 16);
        p += __shfl_xor(p, 32);
        if (lane == 0) out[b] = p + fcfbv + s_yh[TT - 1];
    }
}

extern "C" void kernel_launch(void* const* d_in, const int* in_sizes, int n_in,
                              void* d_out, int out_size, void* d_ws, size_t ws_size,
                              hipStream_t stream) {
    decoder_kernel<<<BB, 512, 0, stream>>>(
        (const float*)d_in[0], (const float*)d_in[1], (const float*)d_in[2],
        (const float*)d_in[3], (const float*)d_in[4], (const float*)d_in[5],
        (const float*)d_in[6], (const float*)d_in[7], (const float*)d_in[8],
        (const float*)d_in[9], (const float*)d_in[10], (const float*)d_in[11],
        (const float*)d_in[12], (const float*)d_in[13], (float*)d_out);
}

// Round 3
// 199.021 us; speedup vs baseline: 1.1775x; 1.1001x over previous
//
#include <hip/hip_runtime.h>

// DA-RNN decoder: 256 blocks (1/CU) x 1024 threads, 32 sequential steps in-block.
// Weights register-resident as f16 pairs consumed by v_dot2_f32_f16 (fp32 accum):
//   tid<512:  one full W_hh gate-row (128 f16 = 64 VGPR), no cross-lane reduce
//   tid>=512: W1a[g, s4*64..+64) slice (64 f16 = 32 VGPR), 4-thread reduce
// Shared h8 wreg[16] for both roles keeps allocation at 64 VGPR. h,c live as f16
// in LDS for dots; c kept fp32 in owner-thread registers (no drift).

#define TT 32

typedef _Float16 h2_t __attribute__((ext_vector_type(2)));
typedef _Float16 h8_t __attribute__((ext_vector_type(8)));

#if __has_builtin(__builtin_amdgcn_fdot2)
#define FDOT2(a, b, c) __builtin_amdgcn_fdot2((a), (b), (c), false)
#else
static __device__ __forceinline__ float FDOT2(h2_t a, h2_t b, float c) {
    return c + (float)a[0] * (float)b[0] + (float)a[1] * (float)b[1];
}
#endif

__device__ __forceinline__ float dot_h8(h8_t w, h8_t v, float acc) {
    acc = FDOT2(__builtin_shufflevector(w, w, 0, 1), __builtin_shufflevector(v, v, 0, 1), acc);
    acc = FDOT2(__builtin_shufflevector(w, w, 2, 3), __builtin_shufflevector(v, v, 2, 3), acc);
    acc = FDOT2(__builtin_shufflevector(w, w, 4, 5), __builtin_shufflevector(v, v, 4, 5), acc);
    acc = FDOT2(__builtin_shufflevector(w, w, 6, 7), __builtin_shufflevector(v, v, 6, 7), acc);
    return acc;
}

__device__ __forceinline__ h8_t pk8(float4 a, float4 b) {
    h8_t r;
    r[0] = (_Float16)a.x; r[1] = (_Float16)a.y; r[2] = (_Float16)a.z; r[3] = (_Float16)a.w;
    r[4] = (_Float16)b.x; r[5] = (_Float16)b.y; r[6] = (_Float16)b.z; r[7] = (_Float16)b.w;
    return r;
}
__device__ __forceinline__ float dot4(float4 a, float4 b) {
    return a.x * b.x + a.y * b.y + a.z * b.z + a.w * b.w;
}
__device__ __forceinline__ float fast_tanh(float x) {
    x = fminf(fmaxf(x, -15.f), 15.f);
    float e = __expf(2.f * x);
    return 1.f - __fdividef(2.f, e + 1.f);
}
__device__ __forceinline__ float fast_sig(float x) {
    return __fdividef(1.f, 1.f + __expf(-x));
}

__global__ __launch_bounds__(1024, 4) void decoder_kernel(
    const float* __restrict__ enc_g,  // [B,T,128]
    const float* __restrict__ yh_g,   // [B,T,1]
    const float* __restrict__ W1,     // [128,384] cols [h|c|enc]
    const float* __restrict__ b1,     // [128]
    const float* __restrict__ W2,     // [1,128]
    const float* __restrict__ b2,     // [1]
    const float* __restrict__ Wih,    // [512,1]
    const float* __restrict__ Whh,    // [512,128]
    const float* __restrict__ bih,    // [512]
    const float* __restrict__ bhh,    // [512]
    const float* __restrict__ fcW,    // [1,129]
    const float* __restrict__ fcB,    // [1]
    const float* __restrict__ fcfW,   // [1,256]
    const float* __restrict__ fcfB,   // [1]
    float* __restrict__ out)          // [B,1]
{
    __shared__ __align__(16) float s_enc[TT * 132];   // [t][132] padded rows
    __shared__ __align__(16) float s_epre[TT * 128];  // W1b@enc + b1 (invariant)
    __shared__ __align__(16) unsigned int s_hc2[128]; // h,c as 256 f16 halves
    __shared__ float s_A[128];
    __shared__ float s_w2[128];
    __shared__ float s_logit[TT];
    __shared__ float s_gdot[512];  // bias + Whh@h
    __shared__ float s_wih[512];
    __shared__ float s_fcw[132];
    __shared__ float s_fcfw[256];
    __shared__ float s_yh[TT];
    __shared__ float s_ytilde;

    const int tid = threadIdx.x;
    const int b = blockIdx.x;
    const int lane = tid & 63;

    // ---- stage ----
    const float4* encp = (const float4*)(enc_g + (size_t)b * TT * 128);
    {
        int t = tid >> 5, e4 = tid & 31;
        *(float4*)(s_enc + t * 132 + e4 * 4) = encp[tid];
    }
    if (tid < 128) {
        s_hc2[tid] = 0u;
        s_w2[tid] = W2[tid];
    }
    if (tid < 512) s_wih[tid] = Wih[tid];
    if (tid < 132) s_fcw[tid] = (tid < 129) ? fcW[tid] : 0.f;
    if (tid < 256) s_fcfw[tid] = fcfW[tid];
    if (tid < TT) s_yh[tid] = yh_g[b * TT + tid];
    const float b2v = b2[0];
    const float fcbv = fcB[0];
    const float fcfbv = fcfB[0];
    __syncthreads();

    // ---- Epre[t][g] = b1[g] + W1[g,256:384] @ enc[t]  (once, fp32) ----
    {
        const int g8 = tid >> 3, s8 = tid & 7;
        const float4* wp = (const float4*)(W1 + g8 * 384 + 256 + s8 * 16);
        float4 w0 = wp[0], w1 = wp[1], w2v_ = wp[2], w3 = wp[3];
        const float b1v = b1[g8];
        for (int t = 0; t < TT; t++) {
            const float4* ep = (const float4*)(s_enc + t * 132 + s8 * 16);
            float pp = dot4(w0, ep[0]) + dot4(w1, ep[1]) + dot4(w2v_, ep[2]) + dot4(w3, ep[3]);
            pp += __shfl_xor(pp, 1);
            pp += __shfl_xor(pp, 2);
            pp += __shfl_xor(pp, 4);
            if (s8 == 0) s_epre[t * 128 + g8] = pp + b1v;
        }
    }

    // ---- persistent f16 weights (shared register array for both roles) ----
    h8_t wreg[16];
    float bias_g = 0.f;
    if (tid < 512) {
        const float4* p = (const float4*)(Whh + (size_t)tid * 128);
#pragma unroll
        for (int k = 0; k < 16; k++) wreg[k] = pk8(p[2 * k], p[2 * k + 1]);
        bias_g = bih[tid] + bhh[tid];
    } else {
        const int u = tid - 512, g = u >> 2, s4 = u & 3;
        const float4* p = (const float4*)(W1 + g * 384 + s4 * 64);
#pragma unroll
        for (int k = 0; k < 8; k++) wreg[k] = pk8(p[2 * k], p[2 * k + 1]);
    }
    float c_reg = 0.f;           // tid<128: fp32 cell state
    float ctxl = 0.f, ctxh = 0.f;  // wave0: ctx[lane], ctx[64+lane]
    __syncthreads();

    // ---- scan over 32 timesteps ----
    for (int t = 0; t < TT; t++) {
        // P1: gdot[row] = bias + Whh[row]@h   (tid<512, full row, no reduce)
        //     A[g]      = W1a[g]@[h;c]        (tid>=512, 4-way split)
        if (tid < 512) {
            const h8_t* hp = (const h8_t*)s_hc2;  // h = halves [0,128) = h8[0..16)
            float a0 = 0.f, a1 = 0.f, a2 = 0.f, a3 = 0.f;
#pragma unroll
            for (int k = 0; k < 4; k++) {
                h8_t v0 = hp[k * 4 + 0], v1 = hp[k * 4 + 1];
                h8_t v2 = hp[k * 4 + 2], v3 = hp[k * 4 + 3];
                a0 = dot_h8(wreg[k * 4 + 0], v0, a0);
                a1 = dot_h8(wreg[k * 4 + 1], v1, a1);
                a2 = dot_h8(wreg[k * 4 + 2], v2, a2);
                a3 = dot_h8(wreg[k * 4 + 3], v3, a3);
            }
            s_gdot[tid] = a0 + a1 + a2 + a3 + bias_g;
        } else {
            const int u = tid - 512, g = u >> 2, s4 = u & 3;
            const h8_t* hcp = (const h8_t*)s_hc2;  // [h;c] = h8[0..32)
            float a0 = 0.f, a1 = 0.f;
#pragma unroll
            for (int k = 0; k < 4; k++) {
                a0 = dot_h8(wreg[2 * k], hcp[s4 * 8 + 2 * k], a0);
                a1 = dot_h8(wreg[2 * k + 1], hcp[s4 * 8 + 2 * k + 1], a1);
            }
            float aa = a0 + a1;
            aa += __shfl_xor(aa, 1);
            aa += __shfl_xor(aa, 2);
            if (s4 == 0) s_A[g] = aa;
        }
        __syncthreads();

        // P2: logits[tt] = b2 + sum_h W2[h]*tanh(A[h]+Epre[tt][h])
        {
            const int tt_ = tid >> 5, hg = tid & 31;
            float4 av = *(const float4*)(s_A + hg * 4);
            float4 ev = *(const float4*)(s_epre + tt_ * 128 + hg * 4);
            float4 wv = *(const float4*)(s_w2 + hg * 4);
            float lp = wv.x * fast_tanh(av.x + ev.x) + wv.y * fast_tanh(av.y + ev.y) +
                       wv.z * fast_tanh(av.z + ev.z) + wv.w * fast_tanh(av.w + ev.w);
            lp += __shfl_xor(lp, 1);
            lp += __shfl_xor(lp, 2);
            lp += __shfl_xor(lp, 4);
            lp += __shfl_xor(lp, 8);
            lp += __shfl_xor(lp, 16);
            if (hg == 0) s_logit[tt_] = lp + b2v;
        }
        __syncthreads();

        // P3 (wave0): softmax (|logit|<~2, no max-sub) -> ctx -> y_tilde
        if (tid < 64) {
            float e = (lane < TT) ? __expf(s_logit[lane]) : 0.f;
            float ssum = e;
            ssum += __shfl_xor(ssum, 1);
            ssum += __shfl_xor(ssum, 2);
            ssum += __shfl_xor(ssum, 4);
            ssum += __shfl_xor(ssum, 8);
            ssum += __shfl_xor(ssum, 16);
            float av_ = __fdividef(e, ssum);  // attn weights in lanes 0..31
            float cl = 0.f, ch = 0.f;
#pragma unroll
            for (int q = 0; q < TT; q++) {
                float a = __shfl(av_, q);
                cl += a * s_enc[q * 132 + lane];
                ch += a * s_enc[q * 132 + 64 + lane];
            }
            ctxl = cl;
            ctxh = ch;
            float yp = s_fcw[lane] * cl + s_fcw[64 + lane] * ch;
            yp += __shfl_xor(yp, 1);
            yp += __shfl_xor(yp, 2);
            yp += __shfl_xor(yp, 4);
            yp += __shfl_xor(yp, 8);
            yp += __shfl_xor(yp, 16);
            yp += __shfl_xor(yp, 32);
            if (lane == 0) s_ytilde = yp + s_fcw[128] * s_yh[t] + fcbv;
        }
        __syncthreads();

        // P4: finish gates + LSTM pointwise (i,f,g,o); h,c -> f16 LDS
        if (tid < 128) {
            const float yt = s_ytilde;
            float gi_ = s_gdot[tid] + s_wih[tid] * yt;
            float gf_ = s_gdot[128 + tid] + s_wih[128 + tid] * yt;
            float gg_ = s_gdot[256 + tid] + s_wih[256 + tid] * yt;
            float go_ = s_gdot[384 + tid] + s_wih[384 + tid] * yt;
            float cn = fast_sig(gf_) * c_reg + fast_sig(gi_) * fast_tanh(gg_);
            float hn = fast_sig(go_) * fast_tanh(cn);
            c_reg = cn;
            _Float16* hp16 = (_Float16*)s_hc2;
            hp16[tid] = (_Float16)hn;
            hp16[128 + tid] = (_Float16)cn;
        }
        __syncthreads();
    }

    // ---- out[b] = fcf_b + fcfW[0:128]@h + fcfW[128:256]@ctx + y_hist[b,31] ----
    if (tid < 64) {
        const _Float16* hp16 = (const _Float16*)s_hc2;
        float h0 = (float)hp16[lane];
        float h1 = (float)hp16[64 + lane];
        float p = s_fcfw[lane] * h0 + s_fcfw[64 + lane] * h1 +
                  s_fcfw[128 + lane] * ctxl + s_fcfw[192 + lane] * ctxh;
        p += __shfl_xor(p, 1);
        p += __shfl_xor(p, 2);
        p += __shfl_xor(p, 4);
        p += __shfl_xor(p, 8);
        p += __shfl_xor(p, 16);
        p += __shfl_xor(p, 32);
        if (lane == 0) out[b] = p + fcfbv + s_yh[TT - 1];
    }
}

extern "C" void kernel_launch(void* const* d_in, const int* in_sizes, int n_in,
                              void* d_out, int out_size, void* d_ws, size_t ws_size,
                              hipStream_t stream) {
    decoder_kernel<<<256, 1024, 0, stream>>>(
        (const float*)d_in[0], (const float*)d_in[1], (const float*)d_in[2],
        (const float*)d_in[3], (const float*)d_in[4], (const float*)d_in[5],
        (const float*)d_in[6], (const float*)d_in[7], (const float*)d_in[8],
        (const float*)d_in[9], (const float*)d_in[10], (const float*)d_in[11],
        (const float*)d_in[12], (const float*)d_in[13], (float*)d_out);
}

// Round 4
// 172.611 us; speedup vs baseline: 1.3576x; 1.1530x over previous
//
#include <hip/hip_runtime.h>

// DA-RNN decoder: 256 blocks (1 per CU) x 1024 threads, 32 sequential steps.
// Whh lives in LDS as f16 (128 KB, XOR-swizzled chunks -> conflict-minimal
// b128 row streams); W1a as f16 in registers (32 VGPR, upper threads only).
// LDS ~153 KB forces 1 block/CU -> compiler VGPR budget 128, no spill.
// Scan step: [G: Whh chunk1 | U: A=W1a@[h;c]] B1 [G: chunk2 | U: logits] B2
//            [G: chunk3+store | P3 wave: softmax + y_tilde via q_t] B3
//            [P4: LSTM pointwise] B4.  y_tilde = (sum_t e_t q_t)/sum(e_t) with
// q_t = fcW.enc_t precomputed; ctx materialized once after the loop.

#define TT 32

typedef _Float16 h2_t __attribute__((ext_vector_type(2)));
typedef _Float16 h4_t __attribute__((ext_vector_type(4)));
typedef _Float16 h8_t __attribute__((ext_vector_type(8)));

#if __has_builtin(__builtin_amdgcn_fdot2)
#define FDOT2(a, b, c) __builtin_amdgcn_fdot2((a), (b), (c), false)
#else
static __device__ __forceinline__ float FDOT2(h2_t a, h2_t b, float c) {
    return c + (float)a[0] * (float)b[0] + (float)a[1] * (float)b[1];
}
#endif

__device__ __forceinline__ float dot_h8(h8_t w, h8_t v, float acc) {
    acc = FDOT2(__builtin_shufflevector(w, w, 0, 1), __builtin_shufflevector(v, v, 0, 1), acc);
    acc = FDOT2(__builtin_shufflevector(w, w, 2, 3), __builtin_shufflevector(v, v, 2, 3), acc);
    acc = FDOT2(__builtin_shufflevector(w, w, 4, 5), __builtin_shufflevector(v, v, 4, 5), acc);
    acc = FDOT2(__builtin_shufflevector(w, w, 6, 7), __builtin_shufflevector(v, v, 6, 7), acc);
    return acc;
}
__device__ __forceinline__ h8_t pk8(float4 a, float4 b) {
    h8_t r;
    r[0] = (_Float16)a.x; r[1] = (_Float16)a.y; r[2] = (_Float16)a.z; r[3] = (_Float16)a.w;
    r[4] = (_Float16)b.x; r[5] = (_Float16)b.y; r[6] = (_Float16)b.z; r[7] = (_Float16)b.w;
    return r;
}
__device__ __forceinline__ float fast_tanh(float x) {
    x = fminf(fmaxf(x, -15.f), 15.f);
    float e = __expf(2.f * x);
    return 1.f - __fdividef(2.f, e + 1.f);
}
__device__ __forceinline__ float fast_sig(float x) {
    return __fdividef(1.f, 1.f + __expf(-x));
}

__global__ __launch_bounds__(1024, 4) void decoder_kernel(
    const float* __restrict__ enc_g,  // [B,32,128]
    const float* __restrict__ yh_g,   // [B,32,1]
    const float* __restrict__ W1,     // [128,384] cols [h|c|enc]
    const float* __restrict__ b1,     // [128]
    const float* __restrict__ W2,     // [1,128]
    const float* __restrict__ b2,     // [1]
    const float* __restrict__ Wih,    // [512,1]
    const float* __restrict__ Whh,    // [512,128]
    const float* __restrict__ bih,    // [512]
    const float* __restrict__ bhh,    // [512]
    const float* __restrict__ fcW,    // [1,129]
    const float* __restrict__ fcB,    // [1]
    const float* __restrict__ fcfW,   // [1,256]
    const float* __restrict__ fcfB,   // [1]
    float* __restrict__ out)          // [B,1]
{
    __shared__ __align__(16) h8_t s_whh8[512 * 16];       // 131072 B, swizzled
    __shared__ __align__(16) _Float16 s_enc16[TT * 136];  // 8704 B (pad 136)
    __shared__ __align__(16) _Float16 s_epre16[TT * 128]; // 8192 B
    __shared__ __align__(16) float s_A[128];
    __shared__ __align__(16) float s_w2[128];
    __shared__ __align__(16) float s_gdot[512];
    __shared__ __align__(16) _Float16 s_wih16[512];
    __shared__ __align__(16) _Float16 s_hc16[256];        // h[128] | c[128]
    __shared__ float s_logit[TT];
    __shared__ float s_q[TT];
    __shared__ float s_att[TT];
    __shared__ float s_yh[TT];
    __shared__ float s_ytilde;

    const int tid = threadIdx.x;
    const int b = blockIdx.x;

    // ================= setup S1: stage enc (f16), Whh->LDS, W1a->regs ========
    {
        const float4* encp = (const float4*)(enc_g + (size_t)b * TT * 128);
        float4 v = encp[tid];  // 1024 float4 total
        int t = tid >> 5, e4 = tid & 31;
        h4_t hv;
        hv[0] = (_Float16)v.x; hv[1] = (_Float16)v.y;
        hv[2] = (_Float16)v.z; hv[3] = (_Float16)v.w;
        *(h4_t*)(s_enc16 + t * 136 + e4 * 4) = hv;
    }
    if (tid < 256) s_hc16[tid] = (_Float16)0.f;
    if (tid < 128) s_w2[tid] = W2[tid];
    if (tid < TT) s_yh[tid] = yh_g[b * TT + tid];

    float bias_r = 0.f;
    h8_t w1a[8];
    if (tid < 512) {
        const int r = tid, rx = r & 15;
        const float4* wp = (const float4*)(Whh + (size_t)r * 128);
#pragma unroll
        for (int c = 0; c < 16; c++)
            s_whh8[(r << 4) | (c ^ rx)] = pk8(wp[2 * c], wp[2 * c + 1]);
        s_wih16[r] = (_Float16)Wih[r];
        bias_r = bih[r] + bhh[r];
    } else {
        const int u = tid - 512, g = u >> 2, s4 = u & 3;
        const float4* p = (const float4*)(W1 + g * 384 + s4 * 64);
#pragma unroll
        for (int k = 0; k < 8; k++) w1a[k] = pk8(p[2 * k], p[2 * k + 1]);
    }
    const float b2v = b2[0];
    const float fcw128 = fcW[128];
    const float fcbv = fcB[0];
    const float fcfbv = fcfB[0];
    __syncthreads();

    // ============ setup S2: Epre (all threads) + q (threads 0..255) ==========
    {
        const int g8 = tid >> 3, s8 = tid & 7;
        const float4* wp = (const float4*)(W1 + g8 * 384 + 256 + s8 * 16);
        h8_t wa = pk8(wp[0], wp[1]);
        h8_t wb = pk8(wp[2], wp[3]);
        const float b1v = b1[g8];
        for (int t = 0; t < TT; t++) {
            const h8_t* ep8 = (const h8_t*)(s_enc16 + t * 136);
            float pa = dot_h8(wa, ep8[s8 * 2], 0.f);
            pa = dot_h8(wb, ep8[s8 * 2 + 1], pa);
            pa += __shfl_xor(pa, 1);
            pa += __shfl_xor(pa, 2);
            pa += __shfl_xor(pa, 4);
            if (s8 == 0) s_epre16[t * 128 + g8] = (_Float16)(pa + b1v);
        }
    }
    if (tid < 256) {  // q[t] = fcW[0:128] . enc[t]
        const int t = tid >> 3, s8 = tid & 7;
        const float4* fp = (const float4*)(fcW + s8 * 16);
        h8_t fa = pk8(fp[0], fp[1]);
        h8_t fb = pk8(fp[2], fp[3]);
        const h8_t* ep8 = (const h8_t*)(s_enc16 + t * 136);
        float pq = dot_h8(fa, ep8[s8 * 2], 0.f);
        pq = dot_h8(fb, ep8[s8 * 2 + 1], pq);
        pq += __shfl_xor(pq, 1);
        pq += __shfl_xor(pq, 2);
        pq += __shfl_xor(pq, 4);
        if (s8 == 0) s_q[t] = pq;
    }
    __syncthreads();

    // ============================ scan (32 steps) ============================
    const h8_t* hcp8 = (const h8_t*)s_hc16;
    float c_reg = 0.f;  // tid<128: fp32 cell state

#define GDOT(c, acc) acc = dot_h8(s_whh8[base | ((c) ^ rx)], hcp8[(c)], acc)

    for (int t = 0; t < TT; t++) {
        float pg0 = 0.f, pg1 = 0.f;  // G partials, live across barriers
        if (tid < 512) {  // G: Whh row stream, chunk 1 (c=0..5)
            const int rx = tid & 15, base = tid << 4;
            GDOT(0, pg0); GDOT(1, pg1); GDOT(2, pg0);
            GDOT(3, pg1); GDOT(4, pg0); GDOT(5, pg1);
        } else {  // U: A[g] = W1a[g] @ [h;c]
            const int u = tid - 512, g = u >> 2, s4 = u & 3;
            float a0 = 0.f, a1 = 0.f;
#pragma unroll
            for (int k = 0; k < 8; k += 2) {
                a0 = dot_h8(w1a[k], hcp8[s4 * 8 + k], a0);
                a1 = dot_h8(w1a[k + 1], hcp8[s4 * 8 + k + 1], a1);
            }
            float aa = a0 + a1;
            aa += __shfl_xor(aa, 1);
            aa += __shfl_xor(aa, 2);
            if (s4 == 0) s_A[g] = aa;
        }
        __syncthreads();  // B1

        if (tid < 512) {  // G chunk 2 (c=6..10)
            const int rx = tid & 15, base = tid << 4;
            GDOT(6, pg0); GDOT(7, pg1); GDOT(8, pg0);
            GDOT(9, pg1); GDOT(10, pg0);
        } else {  // P2: logits[tt] = b2 + sum_h w2[h]*tanh(A[h]+Epre[tt][h])
            const int u = tid - 512, tt_ = u >> 4, sub = u & 15;
            h8_t ev = *(const h8_t*)(s_epre16 + tt_ * 128 + sub * 8);
            float4 av0 = *(const float4*)(s_A + sub * 8);
            float4 av1 = *(const float4*)(s_A + sub * 8 + 4);
            float4 wv0 = *(const float4*)(s_w2 + sub * 8);
            float4 wv1 = *(const float4*)(s_w2 + sub * 8 + 4);
            float lp = wv0.x * fast_tanh(av0.x + (float)ev[0]) +
                       wv0.y * fast_tanh(av0.y + (float)ev[1]) +
                       wv0.z * fast_tanh(av0.z + (float)ev[2]) +
                       wv0.w * fast_tanh(av0.w + (float)ev[3]) +
                       wv1.x * fast_tanh(av1.x + (float)ev[4]) +
                       wv1.y * fast_tanh(av1.y + (float)ev[5]) +
                       wv1.z * fast_tanh(av1.z + (float)ev[6]) +
                       wv1.w * fast_tanh(av1.w + (float)ev[7]);
            lp += __shfl_xor(lp, 1);
            lp += __shfl_xor(lp, 2);
            lp += __shfl_xor(lp, 4);
            lp += __shfl_xor(lp, 8);
            if (sub == 0) s_logit[tt_] = lp + b2v;
        }
        __syncthreads();  // B2

        if (tid < 512) {  // G chunk 3 (c=11..15) + store gate dot
            const int rx = tid & 15, base = tid << 4;
            GDOT(11, pg1); GDOT(12, pg0); GDOT(13, pg1);
            GDOT(14, pg0); GDOT(15, pg1);
            s_gdot[tid] = pg0 + pg1 + bias_r;
        } else if (tid < 576) {  // P3 wave: softmax + y_tilde via q_t
            const int lane = tid & 63;
            float el = 0.f, ql = 0.f;
            if (lane < TT) { el = __expf(s_logit[lane]); ql = s_q[lane]; }
            float ss = el, ys = el * ql;
#pragma unroll
            for (int m = 1; m < 64; m <<= 1) {
                ss += __shfl_xor(ss, m);
                ys += __shfl_xor(ys, m);
            }
            float inv = __fdividef(1.f, ss);
            if (lane < TT) s_att[lane] = el * inv;
            if (lane == 0) s_ytilde = ys * inv + fcw128 * s_yh[t] + fcbv;
        }
        __syncthreads();  // B3

        if (tid < 128) {  // P4: finish gates + LSTM pointwise (i,f,g,o)
            const float yt = s_ytilde;
            float gi_ = s_gdot[tid] + (float)s_wih16[tid] * yt;
            float gf_ = s_gdot[128 + tid] + (float)s_wih16[128 + tid] * yt;
            float gg_ = s_gdot[256 + tid] + (float)s_wih16[256 + tid] * yt;
            float go_ = s_gdot[384 + tid] + (float)s_wih16[384 + tid] * yt;
            float cn = fast_sig(gf_) * c_reg + fast_sig(gi_) * fast_tanh(gg_);
            float hn = fast_sig(go_) * fast_tanh(cn);
            c_reg = cn;
            s_hc16[tid] = (_Float16)hn;
            s_hc16[128 + tid] = (_Float16)cn;
        }
        __syncthreads();  // B4
    }
#undef GDOT

    // ====== out[b] = fcfW[0:128].h + fcfW[128:256].ctx + fcfb + yh[31] =======
    if (tid >= 512 && tid < 576) {
        const int lane = tid & 63;
        float c0 = 0.f, c1 = 0.f;
        for (int t = 0; t < TT; t++) {
            float a = s_att[t];
            c0 += a * (float)s_enc16[t * 136 + lane];
            c1 += a * (float)s_enc16[t * 136 + 64 + lane];
        }
        float h0 = (float)s_hc16[lane];
        float h1 = (float)s_hc16[64 + lane];
        float p = fcfW[lane] * h0 + fcfW[64 + lane] * h1 +
                  fcfW[128 + lane] * c0 + fcfW[192 + lane] * c1;
#pragma unroll
        for (int m = 1; m < 64; m <<= 1) p += __shfl_xor(p, m);
        if (lane == 0) out[b] = p + fcfbv + s_yh[TT - 1];
    }
}

extern "C" void kernel_launch(void* const* d_in, const int* in_sizes, int n_in,
                              void* d_out, int out_size, void* d_ws, size_t ws_size,
                              hipStream_t stream) {
    decoder_kernel<<<256, 1024, 0, stream>>>(
        (const float*)d_in[0], (const float*)d_in[1], (const float*)d_in[2],
        (const float*)d_in[3], (const float*)d_in[4], (const float*)d_in[5],
        (const float*)d_in[6], (const float*)d_in[7], (const float*)d_in[8],
        (const float*)d_in[9], (const float*)d_in[10], (const float*)d_in[11],
        (const float*)d_in[12], (const float*)d_in[13], (float*)d_out);
}